// Round 6
// baseline (258.667 us; speedup 1.0000x reference)
//
#include <hip/hip_runtime.h>
#include <hip/hip_bf16.h>

typedef __attribute__((ext_vector_type(8))) short bf16x8;
typedef __attribute__((ext_vector_type(4))) float f32x4;

#define T_TOK 4096
#define HDIM  1024
#define IDIM  768
#define NEXP  8
#define TOPK  2
#define NSLOT (T_TOK * TOPK)   // 8192 token-slots

#define BM  128
#define BN  64
#define BKS 32                 // K elements per LDS tile (1 MFMA k-step)

#define NX4 (T_TOK * HDIM / 4)
#define NW4 (NEXP * IDIM * HDIM / 4)

__device__ __forceinline__ ushort f2bf(float f) {
  union { __hip_bfloat16 h; ushort u; } cv;
  cv.h = __float2bfloat16(f);
  return cv.u;
}
__device__ __forceinline__ float bf2f(ushort u) {
  union { float f; uint v; } cv; cv.v = ((uint)u) << 16; return cv.f;
}

__device__ __forceinline__ void gload_lds16(const ushort* g, ushort* l) {
  __builtin_amdgcn_global_load_lds(
      (const __attribute__((address_space(1))) void*)g,
      (__attribute__((address_space(3))) void*)l, 16, 0, 0);
}

// ---- fused fp32 -> bf16 conversion of x + 3 weight tensors ----
__global__ void cvt_all(const float* __restrict__ hs, const float* __restrict__ gw,
                        const float* __restrict__ uw, const float* __restrict__ dw,
                        ushort* __restrict__ xb, ushort* __restrict__ gwb,
                        ushort* __restrict__ uwb, ushort* __restrict__ dwb) {
  int i = blockIdx.x * blockDim.x + threadIdx.x;
  const float* src; ushort* dst; int off;
  if (i < NX4) { src = hs; dst = xb; off = i; }
  else {
    int j = i - NX4;
    if (j < NW4)            { src = gw; dst = gwb; off = j; }
    else if (j < 2 * NW4)   { src = uw; dst = uwb; off = j - NW4; }
    else                    { src = dw; dst = dwb; off = j - 2 * NW4; }
  }
  float4 v = reinterpret_cast<const float4*>(src)[off];
  ushort4 o;
  o.x = f2bf(v.x); o.y = f2bf(v.y); o.z = f2bf(v.z); o.w = f2bf(v.w);
  reinterpret_cast<ushort4*>(dst)[off] = o;
}

// ---- build per-expert slot lists ----
__global__ void route_kernel(const int* __restrict__ sel, int* __restrict__ counts,
                             int* __restrict__ toklist) {
  int slot = blockIdx.x * blockDim.x + threadIdx.x;
  if (slot >= NSLOT) return;
  int e = sel[slot];
  int idx = atomicAdd(&counts[e], 1);
  toklist[e * NSLOT + idx] = slot;
}

// swizzle: read (row r, chunk c) at stored chunk c ^ ((r>>1)&3);
// stage lane l fetches global chunk (l&3)^((l>>3)&3) (same involution, inverse side)

// ---- GEMM1: act[slot] = silu(x @ Wg^T) * (x @ Wu^T), grouped by expert ----
// 3-buffer counted-vmcnt pipeline (T3/T4-minimal): vmcnt(4), raw barrier, stage t+2, compute t.
__launch_bounds__(256, 3)
__global__ void gemm_gateup(const ushort* __restrict__ xb,
                            const ushort* __restrict__ gwb,
                            const ushort* __restrict__ uwb,
                            const int* __restrict__ counts,
                            const int* __restrict__ toklist,
                            ushort* __restrict__ act) {
  const int b = blockIdx.x;
  const int e = b & 7;                    // expert == XCD (L2 locality)
  const int r = b >> 3;
  const int nt = r % 12, mt = r / 12;     // mt slowest -> active blocks front-loaded
  const int cnt = counts[e];
  const int m0 = mt * BM;
  if (m0 >= cnt) return;
  const int n0 = nt * BN;

  __shared__ __align__(16) ushort As[3][BM * BKS];    // 3 x 8 KB
  __shared__ __align__(16) ushort Bgs[3][BN * BKS];   // 3 x 4 KB
  __shared__ __align__(16) ushort Bus[3][BN * BKS];   // 3 x 4 KB  = 48 KB

  const int tid = threadIdx.x;
  const int wave = tid >> 6, lane = tid & 63;
  const int wm = wave >> 1, wn = wave & 1;            // 2x2 waves, 64x32 out each
  const int lrow = lane & 15, lk16 = lane >> 4;
  const int rl = lane >> 2;                           // row within 16-row segment
  const int gck = ((lane & 3) ^ ((lane >> 3) & 3)) << 3;

  const int ent0 = m0 + wave * 16 + rl;
  const int ent1 = ent0 + 64;
  const int arow0 = (ent0 < cnt) ? (toklist[e * NSLOT + ent0] >> 1) : 0;
  const int arow1 = (ent1 < cnt) ? (toklist[e * NSLOT + ent1] >> 1) : 0;
  const int brow = wave * 16 + rl;                    // 0..63

  const ushort* aP0 = xb + (size_t)arow0 * HDIM + gck;
  const ushort* aP1 = xb + (size_t)arow1 * HDIM + gck;
  const ushort* gP = gwb + (size_t)e * IDIM * HDIM + (size_t)(n0 + brow) * HDIM + gck;
  const ushort* uP = uwb + (size_t)e * IDIM * HDIM + (size_t)(n0 + brow) * HDIM + gck;

  f32x4 accg[4][2], accu[4][2];
  const f32x4 fzero = {0.f, 0.f, 0.f, 0.f};
  #pragma unroll
  for (int a = 0; a < 4; ++a)
    #pragma unroll
    for (int c = 0; c < 2; ++c) { accg[a][c] = fzero; accu[a][c] = fzero; }

  auto stage = [&](ushort* Ab, ushort* Bgb, ushort* Bub, int k0) {
    gload_lds16(aP0 + k0, Ab + wave * 512);           // 4 VMEM ops per lane
    gload_lds16(aP1 + k0, Ab + (wave + 4) * 512);
    gload_lds16(gP + k0, Bgb + wave * 512);
    gload_lds16(uP + k0, Bub + wave * 512);
  };

  const int swzc = ((lk16 ^ ((lrow >> 1) & 3)) << 3);
  auto compute = [&](const ushort* Ab, const ushort* Bgb, const ushort* Bub) {
    bf16x8 aF[4], bgF[2], buF[2];
    #pragma unroll
    for (int mi = 0; mi < 4; ++mi) {
      int rr = wm * 64 + mi * 16 + lrow;
      aF[mi] = *reinterpret_cast<const bf16x8*>(&Ab[rr * 32 + swzc]);
    }
    #pragma unroll
    for (int ni = 0; ni < 2; ++ni) {
      int rr = wn * 32 + ni * 16 + lrow;
      bgF[ni] = *reinterpret_cast<const bf16x8*>(&Bgb[rr * 32 + swzc]);
      buF[ni] = *reinterpret_cast<const bf16x8*>(&Bub[rr * 32 + swzc]);
    }
    #pragma unroll
    for (int mi = 0; mi < 4; ++mi)
      #pragma unroll
      for (int ni = 0; ni < 2; ++ni) {
        accg[mi][ni] = __builtin_amdgcn_mfma_f32_16x16x32_bf16(aF[mi], bgF[ni], accg[mi][ni], 0, 0, 0);
        accu[mi][ni] = __builtin_amdgcn_mfma_f32_16x16x32_bf16(aF[mi], buF[ni], accu[mi][ni], 0, 0, 0);
      }
  };

  ushort *A0 = As[0], *A1 = As[1], *A2 = As[2];
  ushort *G0 = Bgs[0], *G1 = Bgs[1], *G2 = Bgs[2];
  ushort *U0 = Bus[0], *U1 = Bus[1], *U2 = Bus[2];

  const int NT = HDIM / BKS;                          // 32
  stage(A0, G0, U0, 0);
  stage(A1, G1, U1, BKS);

  #pragma unroll 1
  for (int t = 0; t < NT - 1; ++t) {
    asm volatile("s_waitcnt vmcnt(4)" ::: "memory");  // oldest stage (buf t) landed
    __builtin_amdgcn_s_barrier();                     // all waves see buf t; buf t+2 free
    if (t + 2 < NT) stage(A2, G2, U2, (t + 2) * BKS);
    compute(A0, G0, U0);
    ushort* tp;
    tp = A0; A0 = A1; A1 = A2; A2 = tp;
    tp = G0; G0 = G1; G1 = G2; G2 = tp;
    tp = U0; U0 = U1; U1 = U2; U2 = tp;
  }
  asm volatile("s_waitcnt vmcnt(0)" ::: "memory");
  __builtin_amdgcn_s_barrier();
  compute(A0, G0, U0);

  // epilogue: y = silu(g)*u -> bf16 act[slot][col]; C/D: col=lane&15, row=(lane>>4)*4+j
  const int lcol = lane & 15;
  const int lrb = (lane >> 4) * 4;
  #pragma unroll
  for (int mi = 0; mi < 4; ++mi)
    #pragma unroll
    for (int j = 0; j < 4; ++j) {
      int row = wm * 64 + mi * 16 + lrb + j;
      int entry = m0 + row;
      if (entry >= cnt) continue;
      int slot = toklist[e * NSLOT + entry];
      #pragma unroll
      for (int ni = 0; ni < 2; ++ni) {
        int col = n0 + wn * 32 + ni * 16 + lcol;
        float g = accg[mi][ni][j];
        float u = accu[mi][ni][j];
        float y = (g / (1.0f + __expf(-g))) * u;
        act[(size_t)slot * IDIM + col] = f2bf(y);
      }
    }
}

// ---- GEMM2: yact[slot] = act[slot] @ Wd^T (unweighted, no atomics) ----
__launch_bounds__(256, 4)
__global__ void gemm_down(const ushort* __restrict__ act,
                          const ushort* __restrict__ dwb,
                          const int* __restrict__ counts,
                          const int* __restrict__ toklist,
                          ushort* __restrict__ yact) {
  const int b = blockIdx.x;
  const int e = b & 7;
  const int r = b >> 3;
  const int nt = r & 15, mt = r >> 4;
  const int cnt = counts[e];
  const int m0 = mt * BM;
  if (m0 >= cnt) return;
  const int n0 = nt * BN;

  __shared__ __align__(16) ushort As[3][BM * BKS];    // 3 x 8 KB
  __shared__ __align__(16) ushort Bs[3][BN * BKS];    // 3 x 4 KB  = 36 KB

  const int tid = threadIdx.x;
  const int wave = tid >> 6, lane = tid & 63;
  const int wm = wave >> 1, wn = wave & 1;
  const int lrow = lane & 15, lk16 = lane >> 4;
  const int rl = lane >> 2;
  const int gck = ((lane & 3) ^ ((lane >> 3) & 3)) << 3;

  const int ent0 = m0 + wave * 16 + rl;
  const int ent1 = ent0 + 64;
  const int arow0 = (ent0 < cnt) ? toklist[e * NSLOT + ent0] : 0;  // slot id
  const int arow1 = (ent1 < cnt) ? toklist[e * NSLOT + ent1] : 0;
  const int brow = wave * 16 + rl;

  const ushort* aP0 = act + (size_t)arow0 * IDIM + gck;
  const ushort* aP1 = act + (size_t)arow1 * IDIM + gck;
  const ushort* dP = dwb + (size_t)e * HDIM * IDIM + (size_t)(n0 + brow) * IDIM + gck;

  f32x4 acc[4][2];
  const f32x4 fzero = {0.f, 0.f, 0.f, 0.f};
  #pragma unroll
  for (int a = 0; a < 4; ++a)
    #pragma unroll
    for (int c = 0; c < 2; ++c) acc[a][c] = fzero;

  auto stage = [&](ushort* Ab, ushort* Bb, int k0) {
    gload_lds16(aP0 + k0, Ab + wave * 512);           // 3 VMEM ops per lane
    gload_lds16(aP1 + k0, Ab + (wave + 4) * 512);
    gload_lds16(dP + k0, Bb + wave * 512);
  };

  const int swzc = ((lk16 ^ ((lrow >> 1) & 3)) << 3);
  auto compute = [&](const ushort* Ab, const ushort* Bb) {
    bf16x8 aF[4], bF[2];
    #pragma unroll
    for (int mi = 0; mi < 4; ++mi) {
      int rr = wm * 64 + mi * 16 + lrow;
      aF[mi] = *reinterpret_cast<const bf16x8*>(&Ab[rr * 32 + swzc]);
    }
    #pragma unroll
    for (int ni = 0; ni < 2; ++ni) {
      int rr = wn * 32 + ni * 16 + lrow;
      bF[ni] = *reinterpret_cast<const bf16x8*>(&Bb[rr * 32 + swzc]);
    }
    #pragma unroll
    for (int mi = 0; mi < 4; ++mi)
      #pragma unroll
      for (int ni = 0; ni < 2; ++ni)
        acc[mi][ni] = __builtin_amdgcn_mfma_f32_16x16x32_bf16(aF[mi], bF[ni], acc[mi][ni], 0, 0, 0);
  };

  ushort *A0 = As[0], *A1 = As[1], *A2 = As[2];
  ushort *B0 = Bs[0], *B1 = Bs[1], *B2 = Bs[2];

  const int NT = IDIM / BKS;                          // 24
  stage(A0, B0, 0);
  stage(A1, B1, BKS);

  #pragma unroll 1
  for (int t = 0; t < NT - 1; ++t) {
    asm volatile("s_waitcnt vmcnt(3)" ::: "memory");
    __builtin_amdgcn_s_barrier();
    if (t + 2 < NT) stage(A2, B2, (t + 2) * BKS);
    compute(A0, B0);
    ushort* tp;
    tp = A0; A0 = A1; A1 = A2; A2 = tp;
    tp = B0; B0 = B1; B1 = B2; B2 = tp;
  }
  asm volatile("s_waitcnt vmcnt(0)" ::: "memory");
  __builtin_amdgcn_s_barrier();
  compute(A0, B0);

  const int lcol = lane & 15;
  const int lrb = (lane >> 4) * 4;
  #pragma unroll
  for (int mi = 0; mi < 4; ++mi)
    #pragma unroll
    for (int j = 0; j < 4; ++j) {
      int row = wm * 64 + mi * 16 + lrb + j;
      int entry = m0 + row;
      if (entry >= cnt) continue;
      int slot = toklist[e * NSLOT + entry];
      #pragma unroll
      for (int ni = 0; ni < 2; ++ni) {
        int col = n0 + wn * 32 + ni * 16 + lcol;
        yact[(size_t)slot * HDIM + col] = f2bf(acc[mi][ni][j]);
      }
    }
}

// ---- combine: out[t] = rw[2t]*yact[2t] + rw[2t+1]*yact[2t+1] ----
__global__ void combine_kernel(const ushort* __restrict__ yact, const float* __restrict__ rw,
                               float* __restrict__ out) {
  int i = blockIdx.x * blockDim.x + threadIdx.x;
  int t = i >> 7;
  int h0 = (i & 127) << 3;
  const bf16x8 y0 = *reinterpret_cast<const bf16x8*>(yact + (size_t)(2 * t) * HDIM + h0);
  const bf16x8 y1 = *reinterpret_cast<const bf16x8*>(yact + (size_t)(2 * t + 1) * HDIM + h0);
  float w0 = rw[2 * t], w1 = rw[2 * t + 1];
  float o[8];
  #pragma unroll
  for (int j = 0; j < 8; ++j)
    o[j] = w0 * bf2f((ushort)y0[j]) + w1 * bf2f((ushort)y1[j]);
  float4* op = reinterpret_cast<float4*>(out + (size_t)t * HDIM + h0);
  op[0] = make_float4(o[0], o[1], o[2], o[3]);
  op[1] = make_float4(o[4], o[5], o[6], o[7]);
}

extern "C" void kernel_launch(void* const* d_in, const int* in_sizes, int n_in,
                              void* d_out, int out_size, void* d_ws, size_t ws_size,
                              hipStream_t stream) {
  const float* hs = (const float*)d_in[0];
  const float* rw = (const float*)d_in[1];
  const int*   se = (const int*)d_in[2];
  const float* gw = (const float*)d_in[3];
  const float* uw = (const float*)d_in[4];
  const float* dw = (const float*)d_in[5];
  float* out = (float*)d_out;

  // workspace layout (bytes); yact aliases gwb+uwb (dead after gemm_gateup)
  char* base = (char*)d_ws;
  ushort* xb      = (ushort*)(base + 0);           //  8,388,608
  ushort* gwb     = (ushort*)(base + 8388608);     // 12,582,912
  ushort* uwb     = (ushort*)(base + 20971520);    // 12,582,912
  ushort* dwb     = (ushort*)(base + 33554432);    // 12,582,912
  ushort* act     = (ushort*)(base + 46137344);    // 12,582,912  [slot][IDIM] bf16
  ushort* yact    = (ushort*)(base + 8388608);     // 16,777,216  [slot][HDIM] bf16 (aliases gwb/uwb)
  int*    toklist = (int*)(base + 58720256);       //    262,144
  int*    counts  = (int*)(base + 58982400);       //         32

  hipMemsetAsync(counts, 0, 256, stream);

  int total4 = NX4 + 3 * NW4;
  cvt_all<<<(total4 + 255) / 256, 256, 0, stream>>>(hs, gw, uw, dw, xb, gwb, uwb, dwb);
  route_kernel<<<NSLOT / 256, 256, 0, stream>>>(se, counts, toklist);
  gemm_gateup<<<8 * 12 * (NSLOT / BM), 256, 0, stream>>>(xb, gwb, uwb, counts, toklist, act);
  gemm_down<<<8 * 16 * (NSLOT / BM), 256, 0, stream>>>(act, dwb, counts, toklist, yact);
  combine_kernel<<<T_TOK * HDIM / 8 / 256, 256, 0, stream>>>(yact, rw, out);
}

// Round 8
// 228.049 us; speedup vs baseline: 1.1343x; 1.1343x over previous
//
#include <hip/hip_runtime.h>
#include <hip/hip_bf16.h>

typedef __attribute__((ext_vector_type(8))) short bf16x8;
typedef __attribute__((ext_vector_type(4))) float f32x4;

#define T_TOK 4096
#define HDIM  1024
#define IDIM  768
#define NEXP  8
#define TOPK  2
#define NSLOT (T_TOK * TOPK)   // 8192 token-slots

#define BM  128
#define BN  128
#define BKS 32                 // K elements per LDS tile (1 MFMA k-step)

#define NX4 (T_TOK * HDIM / 4)
#define NW4 (NEXP * IDIM * HDIM / 4)

__device__ __forceinline__ ushort f2bf(float f) {
  union { __hip_bfloat16 h; ushort u; } cv;
  cv.h = __float2bfloat16(f);
  return cv.u;
}
__device__ __forceinline__ float bf2f(ushort u) {
  union { float f; uint v; } cv; cv.v = ((uint)u) << 16; return cv.f;
}

__device__ __forceinline__ void gload_lds16(const ushort* g, ushort* l) {
  __builtin_amdgcn_global_load_lds(
      (const __attribute__((address_space(1))) void*)g,
      (__attribute__((address_space(3))) void*)l, 16, 0, 0);
}

// ---- fused: route (first 32 blocks) + fp32->bf16 conversion (rest) ----
__global__ void cvt_route(const float* __restrict__ hs, const float* __restrict__ gw,
                          const float* __restrict__ uw, const float* __restrict__ dw,
                          ushort* __restrict__ xb, ushort* __restrict__ gwb,
                          ushort* __restrict__ uwb, ushort* __restrict__ dwb,
                          const int* __restrict__ sel, int* __restrict__ counts,
                          int* __restrict__ toklist) {
  int bid = blockIdx.x;
  if (bid < 32) {                       // routing: 32*256 = 8192 slots
    int slot = bid * 256 + threadIdx.x;
    int e = sel[slot];
    int idx = atomicAdd(&counts[e], 1);
    toklist[e * NSLOT + idx] = slot;
    return;
  }
  int i = (bid - 32) * 256 + threadIdx.x;
  const float* src; ushort* dst; int off;
  if (i < NX4) { src = hs; dst = xb; off = i; }
  else {
    int j = i - NX4;
    if (j < NW4)            { src = gw; dst = gwb; off = j; }
    else if (j < 2 * NW4)   { src = uw; dst = uwb; off = j - NW4; }
    else                    { src = dw; dst = dwb; off = j - 2 * NW4; }
  }
  float4 v = reinterpret_cast<const float4*>(src)[off];
  ushort4 o;
  o.x = f2bf(v.x); o.y = f2bf(v.y); o.z = f2bf(v.z); o.w = f2bf(v.w);
  reinterpret_cast<ushort4*>(dst)[off] = o;
}

// swizzle: read (row r, chunk c) at stored chunk c ^ ((r>>1)&3);
// stage lane l fetches global chunk (l&3)^((l>>3)&3) (same involution, inverse side)

// ---- GEMM1: act[slot] = silu(x @ Wg^T) * (x @ Wu^T), 128x128 tile, 2-buffer ----
__launch_bounds__(256, 2)
__global__ void gemm_gateup(const ushort* __restrict__ xb,
                            const ushort* __restrict__ gwb,
                            const ushort* __restrict__ uwb,
                            const int* __restrict__ counts,
                            const int* __restrict__ toklist,
                            ushort* __restrict__ act) {
  const int b = blockIdx.x;
  const int e = b & 7;                    // expert == XCD (L2 locality)
  const int r = b >> 3;
  const int nt = r % 6, mt = r / 6;       // mt slowest -> active blocks front-loaded
  const int cnt = counts[e];
  const int m0 = mt * BM;
  if (m0 >= cnt) return;
  const int n0 = nt * BN;

  __shared__ __align__(16) ushort As[2][BM * BKS];    // 2 x 8 KB
  __shared__ __align__(16) ushort Bgs[2][BM * BKS];   // 2 x 8 KB
  __shared__ __align__(16) ushort Bus[2][BM * BKS];   // 2 x 8 KB  = 48 KB

  const int tid = threadIdx.x;
  const int wave = tid >> 6, lane = tid & 63;
  const int wm = wave >> 1, wn = wave & 1;            // 2x2 waves, 64x64 out each
  const int lrow = lane & 15, lk16 = lane >> 4;
  const int rl = lane >> 2;                           // row within 16-row segment
  const int gck = ((lane & 3) ^ ((lane >> 3) & 3)) << 3;

  const int ent0 = m0 + wave * 16 + rl;
  const int ent1 = ent0 + 64;
  const int arow0 = (ent0 < cnt) ? (toklist[e * NSLOT + ent0] >> 1) : 0;
  const int arow1 = (ent1 < cnt) ? (toklist[e * NSLOT + ent1] >> 1) : 0;
  const int brow0 = wave * 16 + rl;                   // 0..63
  const int brow1 = brow0 + 64;                       // 64..127

  const ushort* aP0 = xb + (size_t)arow0 * HDIM + gck;
  const ushort* aP1 = xb + (size_t)arow1 * HDIM + gck;
  const ushort* wBase = gwb + (size_t)e * IDIM * HDIM;
  const ushort* gP0 = wBase + (size_t)(n0 + brow0) * HDIM + gck;
  const ushort* gP1 = wBase + (size_t)(n0 + brow1) * HDIM + gck;
  const ushort* uBase = uwb + (size_t)e * IDIM * HDIM;
  const ushort* uP0 = uBase + (size_t)(n0 + brow0) * HDIM + gck;
  const ushort* uP1 = uBase + (size_t)(n0 + brow1) * HDIM + gck;

  f32x4 accg[4][4], accu[4][4];
  const f32x4 fzero = {0.f, 0.f, 0.f, 0.f};
  #pragma unroll
  for (int a = 0; a < 4; ++a)
    #pragma unroll
    for (int c = 0; c < 4; ++c) { accg[a][c] = fzero; accu[a][c] = fzero; }

  auto stage = [&](int buf, int k0) {
    gload_lds16(aP0 + k0, &As[buf][wave * 512]);
    gload_lds16(aP1 + k0, &As[buf][(wave + 4) * 512]);
    gload_lds16(gP0 + k0, &Bgs[buf][wave * 512]);
    gload_lds16(gP1 + k0, &Bgs[buf][(wave + 4) * 512]);
    gload_lds16(uP0 + k0, &Bus[buf][wave * 512]);
    gload_lds16(uP1 + k0, &Bus[buf][(wave + 4) * 512]);
  };

  const int swzc = ((lk16 ^ ((lrow >> 1) & 3)) << 3);
  auto compute = [&](int buf) {
    bf16x8 aF[4], bgF[4], buF[4];
    #pragma unroll
    for (int mi = 0; mi < 4; ++mi) {
      int rr = wm * 64 + mi * 16 + lrow;
      aF[mi] = *reinterpret_cast<const bf16x8*>(&As[buf][rr * 32 + swzc]);
    }
    #pragma unroll
    for (int ni = 0; ni < 4; ++ni) {
      int rr = wn * 64 + ni * 16 + lrow;
      bgF[ni] = *reinterpret_cast<const bf16x8*>(&Bgs[buf][rr * 32 + swzc]);
      buF[ni] = *reinterpret_cast<const bf16x8*>(&Bus[buf][rr * 32 + swzc]);
    }
    #pragma unroll
    for (int mi = 0; mi < 4; ++mi)
      #pragma unroll
      for (int ni = 0; ni < 4; ++ni) {
        accg[mi][ni] = __builtin_amdgcn_mfma_f32_16x16x32_bf16(aF[mi], bgF[ni], accg[mi][ni], 0, 0, 0);
        accu[mi][ni] = __builtin_amdgcn_mfma_f32_16x16x32_bf16(aF[mi], buF[ni], accu[mi][ni], 0, 0, 0);
      }
  };

  stage(0, 0);
  __syncthreads();
  #pragma unroll 1
  for (int t = 0; t < HDIM / BKS; t += 2) {
    if (t + 1 < HDIM / BKS) stage(1, (t + 1) * BKS);
    compute(0);
    __syncthreads();
    if (t + 2 < HDIM / BKS) stage(0, (t + 2) * BKS);
    compute(1);
    __syncthreads();
  }

  // epilogue: y = silu(g)*u -> bf16 act[slot][col]; C/D: col=lane&15, row=(lane>>4)*4+j
  const int lcol = lane & 15;
  const int lrb = (lane >> 4) * 4;
  #pragma unroll
  for (int mi = 0; mi < 4; ++mi)
    #pragma unroll
    for (int j = 0; j < 4; ++j) {
      int row = wm * 64 + mi * 16 + lrb + j;
      int entry = m0 + row;
      if (entry >= cnt) continue;
      int slot = toklist[e * NSLOT + entry];
      #pragma unroll
      for (int ni = 0; ni < 4; ++ni) {
        int col = n0 + wn * 64 + ni * 16 + lcol;
        float g = accg[mi][ni][j];
        float u = accu[mi][ni][j];
        float y = (g / (1.0f + __expf(-g))) * u;
        act[(size_t)slot * IDIM + col] = f2bf(y);
      }
    }
}

// ---- GEMM2: yact[slot] = act[slot] @ Wd^T, 128x128 tile, 2-buffer ----
__launch_bounds__(256, 3)
__global__ void gemm_down(const ushort* __restrict__ act,
                          const ushort* __restrict__ dwb,
                          const int* __restrict__ counts,
                          const int* __restrict__ toklist,
                          ushort* __restrict__ yact) {
  const int b = blockIdx.x;
  const int e = b & 7;
  const int r = b >> 3;
  const int nt = r & 7, mt = r >> 3;      // HDIM/BN = 8
  const int cnt = counts[e];
  const int m0 = mt * BM;
  if (m0 >= cnt) return;
  const int n0 = nt * BN;

  __shared__ __align__(16) ushort As[2][BM * BKS];    // 2 x 8 KB
  __shared__ __align__(16) ushort Bs[2][BM * BKS];    // 2 x 8 KB = 32 KB

  const int tid = threadIdx.x;
  const int wave = tid >> 6, lane = tid & 63;
  const int wm = wave >> 1, wn = wave & 1;
  const int lrow = lane & 15, lk16 = lane >> 4;
  const int rl = lane >> 2;
  const int gck = ((lane & 3) ^ ((lane >> 3) & 3)) << 3;

  const int ent0 = m0 + wave * 16 + rl;
  const int ent1 = ent0 + 64;
  const int arow0 = (ent0 < cnt) ? toklist[e * NSLOT + ent0] : 0;  // slot id
  const int arow1 = (ent1 < cnt) ? toklist[e * NSLOT + ent1] : 0;
  const int brow0 = wave * 16 + rl;
  const int brow1 = brow0 + 64;

  const ushort* aP0 = act + (size_t)arow0 * IDIM + gck;
  const ushort* aP1 = act + (size_t)arow1 * IDIM + gck;
  const ushort* dBase = dwb + (size_t)e * HDIM * IDIM;
  const ushort* dP0 = dBase + (size_t)(n0 + brow0) * IDIM + gck;
  const ushort* dP1 = dBase + (size_t)(n0 + brow1) * IDIM + gck;

  f32x4 acc[4][4];
  const f32x4 fzero = {0.f, 0.f, 0.f, 0.f};
  #pragma unroll
  for (int a = 0; a < 4; ++a)
    #pragma unroll
    for (int c = 0; c < 4; ++c) acc[a][c] = fzero;

  auto stage = [&](int buf, int k0) {
    gload_lds16(aP0 + k0, &As[buf][wave * 512]);
    gload_lds16(aP1 + k0, &As[buf][(wave + 4) * 512]);
    gload_lds16(dP0 + k0, &Bs[buf][wave * 512]);
    gload_lds16(dP1 + k0, &Bs[buf][(wave + 4) * 512]);
  };

  const int swzc = ((lk16 ^ ((lrow >> 1) & 3)) << 3);
  auto compute = [&](int buf) {
    bf16x8 aF[4], bF[4];
    #pragma unroll
    for (int mi = 0; mi < 4; ++mi) {
      int rr = wm * 64 + mi * 16 + lrow;
      aF[mi] = *reinterpret_cast<const bf16x8*>(&As[buf][rr * 32 + swzc]);
    }
    #pragma unroll
    for (int ni = 0; ni < 4; ++ni) {
      int rr = wn * 64 + ni * 16 + lrow;
      bF[ni] = *reinterpret_cast<const bf16x8*>(&Bs[buf][rr * 32 + swzc]);
    }
    #pragma unroll
    for (int mi = 0; mi < 4; ++mi)
      #pragma unroll
      for (int ni = 0; ni < 4; ++ni)
        acc[mi][ni] = __builtin_amdgcn_mfma_f32_16x16x32_bf16(aF[mi], bF[ni], acc[mi][ni], 0, 0, 0);
  };

  stage(0, 0);
  __syncthreads();
  #pragma unroll 1
  for (int t = 0; t < IDIM / BKS; t += 2) {
    if (t + 1 < IDIM / BKS) stage(1, (t + 1) * BKS);
    compute(0);
    __syncthreads();
    if (t + 2 < IDIM / BKS) stage(0, (t + 2) * BKS);
    compute(1);
    __syncthreads();
  }

  const int lcol = lane & 15;
  const int lrb = (lane >> 4) * 4;
  #pragma unroll
  for (int mi = 0; mi < 4; ++mi)
    #pragma unroll
    for (int j = 0; j < 4; ++j) {
      int row = wm * 64 + mi * 16 + lrb + j;
      int entry = m0 + row;
      if (entry >= cnt) continue;
      int slot = toklist[e * NSLOT + entry];
      #pragma unroll
      for (int ni = 0; ni < 4; ++ni) {
        int col = n0 + wn * 64 + ni * 16 + lcol;
        yact[(size_t)slot * HDIM + col] = f2bf(acc[mi][ni][j]);
      }
    }
}

// ---- combine: out[t] = rw[2t]*yact[2t] + rw[2t+1]*yact[2t+1] ----
__global__ void combine_kernel(const ushort* __restrict__ yact, const float* __restrict__ rw,
                               float* __restrict__ out) {
  int i = blockIdx.x * blockDim.x + threadIdx.x;
  int t = i >> 7;
  int h0 = (i & 127) << 3;
  const bf16x8 y0 = *reinterpret_cast<const bf16x8*>(yact + (size_t)(2 * t) * HDIM + h0);
  const bf16x8 y1 = *reinterpret_cast<const bf16x8*>(yact + (size_t)(2 * t + 1) * HDIM + h0);
  float w0 = rw[2 * t], w1 = rw[2 * t + 1];
  float o[8];
  #pragma unroll
  for (int j = 0; j < 8; ++j)
    o[j] = w0 * bf2f((ushort)y0[j]) + w1 * bf2f((ushort)y1[j]);
  float4* op = reinterpret_cast<float4*>(out + (size_t)t * HDIM + h0);
  op[0] = make_float4(o[0], o[1], o[2], o[3]);
  op[1] = make_float4(o[4], o[5], o[6], o[7]);
}

extern "C" void kernel_launch(void* const* d_in, const int* in_sizes, int n_in,
                              void* d_out, int out_size, void* d_ws, size_t ws_size,
                              hipStream_t stream) {
  const float* hs = (const float*)d_in[0];
  const float* rw = (const float*)d_in[1];
  const int*   se = (const int*)d_in[2];
  const float* gw = (const float*)d_in[3];
  const float* uw = (const float*)d_in[4];
  const float* dw = (const float*)d_in[5];
  float* out = (float*)d_out;

  // workspace layout (bytes); yact aliases gwb+uwb (dead after gemm_gateup)
  char* base = (char*)d_ws;
  ushort* xb      = (ushort*)(base + 0);           //  8,388,608
  ushort* gwb     = (ushort*)(base + 8388608);     // 12,582,912
  ushort* uwb     = (ushort*)(base + 20971520);    // 12,582,912
  ushort* dwb     = (ushort*)(base + 33554432);    // 12,582,912
  ushort* act     = (ushort*)(base + 46137344);    // 12,582,912  [slot][IDIM] bf16
  ushort* yact    = (ushort*)(base + 8388608);     // 16,777,216  [slot][HDIM] bf16 (aliases gwb/uwb)
  int*    toklist = (int*)(base + 58720256);       //    262,144
  int*    counts  = (int*)(base + 58982400);       //         32

  hipMemsetAsync(counts, 0, 256, stream);

  int total4 = NX4 + 3 * NW4;
  cvt_route<<<32 + (total4 + 255) / 256, 256, 0, stream>>>(hs, gw, uw, dw, xb, gwb, uwb, dwb,
                                                           se, counts, toklist);
  gemm_gateup<<<8 * 6 * (NSLOT / BM), 256, 0, stream>>>(xb, gwb, uwb, counts, toklist, act);
  gemm_down<<<8 * 8 * (NSLOT / BM), 256, 0, stream>>>(act, dwb, counts, toklist, yact);
  combine_kernel<<<T_TOK * HDIM / 8 / 256, 256, 0, stream>>>(yact, rw, out);
}

// Round 9
// 224.751 us; speedup vs baseline: 1.1509x; 1.0147x over previous
//
#include <hip/hip_runtime.h>
#include <hip/hip_bf16.h>

typedef __attribute__((ext_vector_type(8))) short bf16x8;
typedef __attribute__((ext_vector_type(8))) ushort ushort8;
typedef __attribute__((ext_vector_type(4))) float f32x4;

#define T_TOK 4096
#define HDIM  1024
#define IDIM  768
#define NEXP  8
#define TOPK  2
#define NSLOT (T_TOK * TOPK)   // 8192 token-slots

#define BM  128
#define BN  128
#define BKS 32                 // K elements per LDS tile (1 MFMA k-step)

#define NX4 (T_TOK * HDIM / 4)
#define NW4 (NEXP * IDIM * HDIM / 4)
#define NX8 (NX4 / 2)
#define NW8 (NW4 / 2)

__device__ __forceinline__ ushort f2bf(float f) {
  union { __hip_bfloat16 h; ushort u; } cv;
  cv.h = __float2bfloat16(f);
  return cv.u;
}
__device__ __forceinline__ float bf2f(ushort u) {
  union { float f; uint v; } cv; cv.v = ((uint)u) << 16; return cv.f;
}

__device__ __forceinline__ void gload_lds16(const ushort* g, ushort* l) {
  __builtin_amdgcn_global_load_lds(
      (const __attribute__((address_space(1))) void*)g,
      (__attribute__((address_space(3))) void*)l, 16, 0, 0);
}

// ---- fused: route (first 32 blocks) + fp32->bf16 conversion (rest) ----
// cvt: each thread converts TWO float4s -> one ushort8 (32B read / 16B write)
__global__ void cvt_route(const float* __restrict__ hs, const float* __restrict__ gw,
                          const float* __restrict__ uw, const float* __restrict__ dw,
                          ushort* __restrict__ xb, ushort* __restrict__ gwb,
                          ushort* __restrict__ uwb, ushort* __restrict__ dwb,
                          const int* __restrict__ sel, int* __restrict__ counts,
                          int* __restrict__ toklist) {
  int bid = blockIdx.x;
  if (bid < 32) {                       // routing: 32*256 = 8192 slots
    int slot = bid * 256 + threadIdx.x;
    int e = sel[slot];
    int idx = atomicAdd(&counts[e], 1);
    toklist[e * NSLOT + idx] = slot;
    return;
  }
  int i = (bid - 32) * 256 + threadIdx.x;   // pair index (8 floats)
  const float* src; ushort* dst; int off;
  if (i < NX8) { src = hs; dst = xb; off = i; }
  else {
    int j = i - NX8;
    if (j < NW8)            { src = gw; dst = gwb; off = j; }
    else if (j < 2 * NW8)   { src = uw; dst = uwb; off = j - NW8; }
    else                    { src = dw; dst = dwb; off = j - 2 * NW8; }
  }
  const float4* s4 = reinterpret_cast<const float4*>(src) + 2 * (size_t)off;
  float4 v0 = s4[0];
  float4 v1 = s4[1];
  ushort8 o;
  o[0] = f2bf(v0.x); o[1] = f2bf(v0.y); o[2] = f2bf(v0.z); o[3] = f2bf(v0.w);
  o[4] = f2bf(v1.x); o[5] = f2bf(v1.y); o[6] = f2bf(v1.z); o[7] = f2bf(v1.w);
  reinterpret_cast<ushort8*>(dst)[off] = o;
}

// swizzle: read (row r, chunk c) at stored chunk c ^ ((r>>1)&3);
// stage lane l fetches global chunk (l&3)^((l>>3)&3) (same involution, inverse side)

// ---- GEMM1: act[slot] = silu(x @ Wg^T) * (x @ Wu^T), 128x128 tile, 2-buffer ----
__launch_bounds__(256, 2)
__global__ void gemm_gateup(const ushort* __restrict__ xb,
                            const ushort* __restrict__ gwb,
                            const ushort* __restrict__ uwb,
                            const int* __restrict__ counts,
                            const int* __restrict__ toklist,
                            ushort* __restrict__ act) {
  const int b = blockIdx.x;
  const int e = b & 7;                    // expert == XCD (L2 locality)
  const int r = b >> 3;
  const int nt = r % 6, mt = r / 6;       // mt slowest -> active blocks front-loaded
  const int cnt = counts[e];
  const int m0 = mt * BM;
  if (m0 >= cnt) return;
  const int n0 = nt * BN;

  __shared__ __align__(16) ushort As[2][BM * BKS];    // 2 x 8 KB
  __shared__ __align__(16) ushort Bgs[2][BM * BKS];   // 2 x 8 KB
  __shared__ __align__(16) ushort Bus[2][BM * BKS];   // 2 x 8 KB  = 48 KB

  const int tid = threadIdx.x;
  const int wave = tid >> 6, lane = tid & 63;
  const int wm = wave >> 1, wn = wave & 1;            // 2x2 waves, 64x64 out each
  const int lrow = lane & 15, lk16 = lane >> 4;
  const int rl = lane >> 2;                           // row within 16-row segment
  const int gck = ((lane & 3) ^ ((lane >> 3) & 3)) << 3;

  const int ent0 = m0 + wave * 16 + rl;
  const int ent1 = ent0 + 64;
  const int arow0 = (ent0 < cnt) ? (toklist[e * NSLOT + ent0] >> 1) : 0;
  const int arow1 = (ent1 < cnt) ? (toklist[e * NSLOT + ent1] >> 1) : 0;
  const int brow0 = wave * 16 + rl;                   // 0..63
  const int brow1 = brow0 + 64;                       // 64..127

  const ushort* aP0 = xb + (size_t)arow0 * HDIM + gck;
  const ushort* aP1 = xb + (size_t)arow1 * HDIM + gck;
  const ushort* wBase = gwb + (size_t)e * IDIM * HDIM;
  const ushort* gP0 = wBase + (size_t)(n0 + brow0) * HDIM + gck;
  const ushort* gP1 = wBase + (size_t)(n0 + brow1) * HDIM + gck;
  const ushort* uBase = uwb + (size_t)e * IDIM * HDIM;
  const ushort* uP0 = uBase + (size_t)(n0 + brow0) * HDIM + gck;
  const ushort* uP1 = uBase + (size_t)(n0 + brow1) * HDIM + gck;

  f32x4 accg[4][4], accu[4][4];
  const f32x4 fzero = {0.f, 0.f, 0.f, 0.f};
  #pragma unroll
  for (int a = 0; a < 4; ++a)
    #pragma unroll
    for (int c = 0; c < 4; ++c) { accg[a][c] = fzero; accu[a][c] = fzero; }

  auto stage = [&](int buf, int k0) {
    gload_lds16(aP0 + k0, &As[buf][wave * 512]);
    gload_lds16(aP1 + k0, &As[buf][(wave + 4) * 512]);
    gload_lds16(gP0 + k0, &Bgs[buf][wave * 512]);
    gload_lds16(gP1 + k0, &Bgs[buf][(wave + 4) * 512]);
    gload_lds16(uP0 + k0, &Bus[buf][wave * 512]);
    gload_lds16(uP1 + k0, &Bus[buf][(wave + 4) * 512]);
  };

  const int swzc = ((lk16 ^ ((lrow >> 1) & 3)) << 3);
  auto compute = [&](int buf) {
    bf16x8 aF[4], bgF[4], buF[4];
    #pragma unroll
    for (int mi = 0; mi < 4; ++mi) {
      int rr = wm * 64 + mi * 16 + lrow;
      aF[mi] = *reinterpret_cast<const bf16x8*>(&As[buf][rr * 32 + swzc]);
    }
    #pragma unroll
    for (int ni = 0; ni < 4; ++ni) {
      int rr = wn * 64 + ni * 16 + lrow;
      bgF[ni] = *reinterpret_cast<const bf16x8*>(&Bgs[buf][rr * 32 + swzc]);
      buF[ni] = *reinterpret_cast<const bf16x8*>(&Bus[buf][rr * 32 + swzc]);
    }
    #pragma unroll
    for (int mi = 0; mi < 4; ++mi)
      #pragma unroll
      for (int ni = 0; ni < 4; ++ni) {
        accg[mi][ni] = __builtin_amdgcn_mfma_f32_16x16x32_bf16(aF[mi], bgF[ni], accg[mi][ni], 0, 0, 0);
        accu[mi][ni] = __builtin_amdgcn_mfma_f32_16x16x32_bf16(aF[mi], buF[ni], accu[mi][ni], 0, 0, 0);
      }
  };

  stage(0, 0);
  __syncthreads();
  #pragma unroll 1
  for (int t = 0; t < HDIM / BKS; t += 2) {
    if (t + 1 < HDIM / BKS) stage(1, (t + 1) * BKS);
    compute(0);
    __syncthreads();
    if (t + 2 < HDIM / BKS) stage(0, (t + 2) * BKS);
    compute(1);
    __syncthreads();
  }

  // epilogue: y = silu(g)*u -> bf16 act[slot][col]; C/D: col=lane&15, row=(lane>>4)*4+j
  const int lcol = lane & 15;
  const int lrb = (lane >> 4) * 4;
  #pragma unroll
  for (int mi = 0; mi < 4; ++mi)
    #pragma unroll
    for (int j = 0; j < 4; ++j) {
      int row = wm * 64 + mi * 16 + lrb + j;
      int entry = m0 + row;
      if (entry >= cnt) continue;
      int slot = toklist[e * NSLOT + entry];
      #pragma unroll
      for (int ni = 0; ni < 4; ++ni) {
        int col = n0 + wn * 64 + ni * 16 + lcol;
        float g = accg[mi][ni][j];
        float u = accu[mi][ni][j];
        float y = (g / (1.0f + __expf(-g))) * u;
        act[(size_t)slot * IDIM + col] = f2bf(y);
      }
    }
}

// ---- GEMM2: yact[slot] = act[slot] @ Wd^T, 128x128 tile, 2-buffer ----
__launch_bounds__(256, 3)
__global__ void gemm_down(const ushort* __restrict__ act,
                          const ushort* __restrict__ dwb,
                          const int* __restrict__ counts,
                          const int* __restrict__ toklist,
                          ushort* __restrict__ yact) {
  const int b = blockIdx.x;
  const int e = b & 7;
  const int r = b >> 3;
  const int nt = r & 7, mt = r >> 3;      // HDIM/BN = 8
  const int cnt = counts[e];
  const int m0 = mt * BM;
  if (m0 >= cnt) return;
  const int n0 = nt * BN;

  __shared__ __align__(16) ushort As[2][BM * BKS];    // 2 x 8 KB
  __shared__ __align__(16) ushort Bs[2][BM * BKS];    // 2 x 8 KB = 32 KB

  const int tid = threadIdx.x;
  const int wave = tid >> 6, lane = tid & 63;
  const int wm = wave >> 1, wn = wave & 1;
  const int lrow = lane & 15, lk16 = lane >> 4;
  const int rl = lane >> 2;
  const int gck = ((lane & 3) ^ ((lane >> 3) & 3)) << 3;

  const int ent0 = m0 + wave * 16 + rl;
  const int ent1 = ent0 + 64;
  const int arow0 = (ent0 < cnt) ? toklist[e * NSLOT + ent0] : 0;  // slot id
  const int arow1 = (ent1 < cnt) ? toklist[e * NSLOT + ent1] : 0;
  const int brow0 = wave * 16 + rl;
  const int brow1 = brow0 + 64;

  const ushort* aP0 = act + (size_t)arow0 * IDIM + gck;
  const ushort* aP1 = act + (size_t)arow1 * IDIM + gck;
  const ushort* dBase = dwb + (size_t)e * HDIM * IDIM;
  const ushort* dP0 = dBase + (size_t)(n0 + brow0) * IDIM + gck;
  const ushort* dP1 = dBase + (size_t)(n0 + brow1) * IDIM + gck;

  f32x4 acc[4][4];
  const f32x4 fzero = {0.f, 0.f, 0.f, 0.f};
  #pragma unroll
  for (int a = 0; a < 4; ++a)
    #pragma unroll
    for (int c = 0; c < 4; ++c) acc[a][c] = fzero;

  auto stage = [&](int buf, int k0) {
    gload_lds16(aP0 + k0, &As[buf][wave * 512]);
    gload_lds16(aP1 + k0, &As[buf][(wave + 4) * 512]);
    gload_lds16(dP0 + k0, &Bs[buf][wave * 512]);
    gload_lds16(dP1 + k0, &Bs[buf][(wave + 4) * 512]);
  };

  const int swzc = ((lk16 ^ ((lrow >> 1) & 3)) << 3);
  auto compute = [&](int buf) {
    bf16x8 aF[4], bF[4];
    #pragma unroll
    for (int mi = 0; mi < 4; ++mi) {
      int rr = wm * 64 + mi * 16 + lrow;
      aF[mi] = *reinterpret_cast<const bf16x8*>(&As[buf][rr * 32 + swzc]);
    }
    #pragma unroll
    for (int ni = 0; ni < 4; ++ni) {
      int rr = wn * 64 + ni * 16 + lrow;
      bF[ni] = *reinterpret_cast<const bf16x8*>(&Bs[buf][rr * 32 + swzc]);
    }
    #pragma unroll
    for (int mi = 0; mi < 4; ++mi)
      #pragma unroll
      for (int ni = 0; ni < 4; ++ni)
        acc[mi][ni] = __builtin_amdgcn_mfma_f32_16x16x32_bf16(aF[mi], bF[ni], acc[mi][ni], 0, 0, 0);
  };

  stage(0, 0);
  __syncthreads();
  #pragma unroll 1
  for (int t = 0; t < IDIM / BKS; t += 2) {
    if (t + 1 < IDIM / BKS) stage(1, (t + 1) * BKS);
    compute(0);
    __syncthreads();
    if (t + 2 < IDIM / BKS) stage(0, (t + 2) * BKS);
    compute(1);
    __syncthreads();
  }

  const int lcol = lane & 15;
  const int lrb = (lane >> 4) * 4;
  #pragma unroll
  for (int mi = 0; mi < 4; ++mi)
    #pragma unroll
    for (int j = 0; j < 4; ++j) {
      int row = wm * 64 + mi * 16 + lrb + j;
      int entry = m0 + row;
      if (entry >= cnt) continue;
      int slot = toklist[e * NSLOT + entry];
      #pragma unroll
      for (int ni = 0; ni < 4; ++ni) {
        int col = n0 + wn * 64 + ni * 16 + lcol;
        yact[(size_t)slot * HDIM + col] = f2bf(acc[mi][ni][j]);
      }
    }
}

// ---- combine: out[t] = rw[2t]*yact[2t] + rw[2t+1]*yact[2t+1] ----
__global__ void combine_kernel(const ushort* __restrict__ yact, const float* __restrict__ rw,
                               float* __restrict__ out) {
  int i = blockIdx.x * blockDim.x + threadIdx.x;
  int t = i >> 7;
  int h0 = (i & 127) << 3;
  const bf16x8 y0 = *reinterpret_cast<const bf16x8*>(yact + (size_t)(2 * t) * HDIM + h0);
  const bf16x8 y1 = *reinterpret_cast<const bf16x8*>(yact + (size_t)(2 * t + 1) * HDIM + h0);
  float w0 = rw[2 * t], w1 = rw[2 * t + 1];
  float o[8];
  #pragma unroll
  for (int j = 0; j < 8; ++j)
    o[j] = w0 * bf2f((ushort)y0[j]) + w1 * bf2f((ushort)y1[j]);
  float4* op = reinterpret_cast<float4*>(out + (size_t)t * HDIM + h0);
  op[0] = make_float4(o[0], o[1], o[2], o[3]);
  op[1] = make_float4(o[4], o[5], o[6], o[7]);
}

extern "C" void kernel_launch(void* const* d_in, const int* in_sizes, int n_in,
                              void* d_out, int out_size, void* d_ws, size_t ws_size,
                              hipStream_t stream) {
  const float* hs = (const float*)d_in[0];
  const float* rw = (const float*)d_in[1];
  const int*   se = (const int*)d_in[2];
  const float* gw = (const float*)d_in[3];
  const float* uw = (const float*)d_in[4];
  const float* dw = (const float*)d_in[5];
  float* out = (float*)d_out;

  // workspace layout (bytes); yact aliases gwb+uwb (dead after gemm_gateup)
  char* base = (char*)d_ws;
  ushort* xb      = (ushort*)(base + 0);           //  8,388,608
  ushort* gwb     = (ushort*)(base + 8388608);     // 12,582,912
  ushort* uwb     = (ushort*)(base + 20971520);    // 12,582,912
  ushort* dwb     = (ushort*)(base + 33554432);    // 12,582,912
  ushort* act     = (ushort*)(base + 46137344);    // 12,582,912  [slot][IDIM] bf16
  ushort* yact    = (ushort*)(base + 8388608);     // 16,777,216  [slot][HDIM] bf16 (aliases gwb/uwb)
  int*    toklist = (int*)(base + 58720256);       //    262,144
  int*    counts  = (int*)(base + 58982400);       //         32

  hipMemsetAsync(counts, 0, 256, stream);

  int total8 = NX8 + 3 * NW8;                      // 2,883,584 pairs
  cvt_route<<<32 + (total8 + 255) / 256, 256, 0, stream>>>(hs, gw, uw, dw, xb, gwb, uwb, dwb,
                                                           se, counts, toklist);
  gemm_gateup<<<8 * 6 * (NSLOT / BM), 256, 0, stream>>>(xb, gwb, uwb, counts, toklist, act);
  gemm_down<<<8 * 8 * (NSLOT / BM), 256, 0, stream>>>(act, dwb, counts, toklist, yact);
  combine_kernel<<<T_TOK * HDIM / 8 / 256, 256, 0, stream>>>(yact, rw, out);
}